// Round 1
// baseline (66929.285 us; speedup 1.0000x reference)
//
#include <hip/hip_runtime.h>

#define T_SEQ 16384
#define HID   128
#define G4    512   // 4*HID

typedef _Float16 half2t __attribute__((ext_vector_type(2)));

__device__ __forceinline__ float sigm(float x) {
    // 1/(1+2^(-x*log2e)); inf-safe: rcp(inf)=0
    float e = __expf(-x);
    return __builtin_amdgcn_rcpf(1.0f + e);
}
__device__ __forceinline__ float tanh_(float x) {
    // tanh(x) = 2/(1+e^{-2x}) - 1
    float e = __expf(-2.0f * x);
    return __builtin_amdgcn_rcpf(1.0f + e) * 2.0f - 1.0f;
}

__device__ __forceinline__ half2t pack2(float lo, float hi) {
    half2t v; v.x = (_Float16)lo; v.y = (_Float16)hi; return v;
}

// ---------------------------------------------------------------------------
// Kernel 1: pre1[t][r] = (b_ih1[r]+b_hh1[r]) + sum_k x[t][k]*W_ih1[r][k]
// block = 512 threads (one per output row r), 16 timesteps per block.
// ---------------------------------------------------------------------------
__global__ __launch_bounds__(512, 1)
void pre1_gemm(const float* __restrict__ x, const float* __restrict__ Wih1,
               const float* __restrict__ bih1, const float* __restrict__ bhh1,
               float* __restrict__ pre1)
{
    __shared__ float xs[16][50];
    const int r  = threadIdx.x;
    const int t0 = blockIdx.x * 16;
    for (int i = r; i < 16 * 50; i += 512) xs[i / 50][i % 50] = x[t0 * 50 + i];
    __syncthreads();

    float wr[50];
#pragma unroll
    for (int k = 0; k < 50; ++k) wr[k] = Wih1[r * 50 + k];
    const float bias = bih1[r] + bhh1[r];

    for (int tt = 0; tt < 16; ++tt) {
        float acc = bias;
#pragma unroll
        for (int k = 0; k < 50; ++k) acc = fmaf(wr[k], xs[tt][k], acc);
        pre1[(size_t)(t0 + tt) * G4 + r] = acc;
    }
}

// ---------------------------------------------------------------------------
// Kernel 2: the sequential 2-layer LSTM scan. ONE workgroup, 512 threads.
// Layer 2 runs one step lagged so all matvecs per superstep only read
// previous-superstep state (h1[s-1], h2[s-2]) -> fully concurrent issue.
// Thread (w,l): wave w=tid>>6, lane l=tid&63; gate gid=l>>4, unit uu=16w+(l&15);
// owns row r = gid*128+uu of all three weight matrices (packed f16 in VGPRs).
// Gate math: waves 0-1 -> layer-1 units 0..127; waves 2-3 -> layer-2 units.
// ---------------------------------------------------------------------------
__global__ __launch_bounds__(512, 1)
void lstm_scan(const float* __restrict__ pre1,
               const float* __restrict__ Whh1,
               const float* __restrict__ Wih2,
               const float* __restrict__ Whh2,
               const float* __restrict__ bih2,
               const float* __restrict__ bhh2,
               float* __restrict__ h2out)
{
    const int tid = threadIdx.x;
    const int w   = tid >> 6;
    const int l   = tid & 63;
    const int gid = l >> 4;
    const int uu  = (w << 4) | (l & 15);
    const int r   = (gid << 7) | uu;          // row in [0,512)

    __shared__ __align__(16) _Float16 H1[2][HID];   // h1 state, f16, double-buffered
    __shared__ __align__(16) _Float16 H2[2][HID];
    __shared__ float gx[2][G4];                     // pre-activation exchange

    {   // zero initial state (h1[-1]=h2[-1]=0)
        _Float16* p1 = &H1[0][0];
        _Float16* p2 = &H2[0][0];
        for (int k = tid; k < 2 * HID; k += 512) { p1[k] = (_Float16)0.f; p2[k] = (_Float16)0.f; }
    }

    // ---- load weights into registers as packed f16 (64+64+64 VGPRs) ----
    half2t w1[64], w2a[64], w2b[64];
    {
        const float2* a = (const float2*)(Whh1 + (size_t)r * HID);
        const float2* b = (const float2*)(Wih2 + (size_t)r * HID);
        const float2* c = (const float2*)(Whh2 + (size_t)r * HID);
#pragma unroll
        for (int k = 0; k < 64; ++k) {
            float2 va = a[k], vb = b[k], vc = c[k];
            w1[k]  = pack2(va.x, va.y);
            w2a[k] = pack2(vb.x, vb.y);
            w2b[k] = pack2(vc.x, vc.y);
        }
    }
    const float bias2 = bih2[r] + bhh2[r];

    // gate-phase unit assignment
    const int gu1 = (w << 6) | l;          // valid for waves 0-1: units 0..127
    const int gu2 = ((w - 2) << 6) | l;    // valid for waves 2-3
    float c1 = 0.f, c2 = 0.f;

    const float* prep = pre1 + r;          // pre1[s][r] walker
    float pre_cur = prep[0];
    __syncthreads();

    for (int s = 0; s <= T_SEQ; ++s) {
        const int rs = s & 1;
        const int wslot = rs ^ 1;

        // prefetch next step's pre1 value (used next iteration)
        float pre_nxt = 0.f;
        if (s + 1 < T_SEQ) pre_nxt = prep[(size_t)(s + 1) * G4];

        // ---------------- dot phase (reads only slot rs) ----------------
        if (s < T_SEQ) {  // layer 1, step s
            const float4* hp = (const float4*)&H1[rs][0];
            float a0 = pre_cur, a1 = 0.f, a2 = 0.f, a3 = 0.f;
#pragma unroll
            for (int kc = 0; kc < 16; ++kc) {
                float4 v = hp[kc];
                a0 = __builtin_amdgcn_fdot2(w1[4 * kc + 0], __builtin_bit_cast(half2t, v.x), a0, false);
                a1 = __builtin_amdgcn_fdot2(w1[4 * kc + 1], __builtin_bit_cast(half2t, v.y), a1, false);
                a2 = __builtin_amdgcn_fdot2(w1[4 * kc + 2], __builtin_bit_cast(half2t, v.z), a2, false);
                a3 = __builtin_amdgcn_fdot2(w1[4 * kc + 3], __builtin_bit_cast(half2t, v.w), a3, false);
            }
            gx[0][r] = (a0 + a1) + (a2 + a3);
        }
        if (s >= 1) {     // layer 2, step s-1
            const float4* hp1 = (const float4*)&H1[rs][0];
            const float4* hp2 = (const float4*)&H2[rs][0];
            float a0 = bias2, a1 = 0.f, a2 = 0.f, a3 = 0.f;
#pragma unroll
            for (int kc = 0; kc < 16; ++kc) {
                float4 v = hp1[kc];
                a0 = __builtin_amdgcn_fdot2(w2a[4 * kc + 0], __builtin_bit_cast(half2t, v.x), a0, false);
                a1 = __builtin_amdgcn_fdot2(w2a[4 * kc + 1], __builtin_bit_cast(half2t, v.y), a1, false);
                a2 = __builtin_amdgcn_fdot2(w2a[4 * kc + 2], __builtin_bit_cast(half2t, v.z), a2, false);
                a3 = __builtin_amdgcn_fdot2(w2a[4 * kc + 3], __builtin_bit_cast(half2t, v.w), a3, false);
            }
#pragma unroll
            for (int kc = 0; kc < 16; ++kc) {
                float4 v = hp2[kc];
                a0 = __builtin_amdgcn_fdot2(w2b[4 * kc + 0], __builtin_bit_cast(half2t, v.x), a0, false);
                a1 = __builtin_amdgcn_fdot2(w2b[4 * kc + 1], __builtin_bit_cast(half2t, v.y), a1, false);
                a2 = __builtin_amdgcn_fdot2(w2b[4 * kc + 2], __builtin_bit_cast(half2t, v.z), a2, false);
                a3 = __builtin_amdgcn_fdot2(w2b[4 * kc + 3], __builtin_bit_cast(half2t, v.w), a3, false);
            }
            gx[1][r] = (a0 + a1) + (a2 + a3);
        }
        __syncthreads();

        // ---------------- gate phase (writes slot wslot) ----------------
        if (s < T_SEQ && w < 2) {           // layer-1 gates, unit gu1
            const float* g = &gx[0][0];
            float i_ = sigm(g[gu1]);
            float f_ = sigm(g[HID + gu1]);
            float gg = tanh_(g[2 * HID + gu1]);
            float o_ = sigm(g[3 * HID + gu1]);
            c1 = f_ * c1 + i_ * gg;
            H1[wslot][gu1] = (_Float16)(o_ * tanh_(c1));
        }
        if (s >= 1 && w >= 2 && w < 4) {    // layer-2 gates, unit gu2, step s-1
            const float* g = &gx[1][0];
            float i_ = sigm(g[gu2]);
            float f_ = sigm(g[HID + gu2]);
            float gg = tanh_(g[2 * HID + gu2]);
            float o_ = sigm(g[3 * HID + gu2]);
            c2 = f_ * c2 + i_ * gg;
            float h = o_ * tanh_(c2);
            H2[wslot][gu2] = (_Float16)h;
            h2out[(size_t)(s - 1) * HID + gu2] = h;   // fp32 for the FC epilogue
        }
        __syncthreads();

        pre_cur = pre_nxt;
    }
}

// ---------------------------------------------------------------------------
// Kernel 3: out[t][o] = fc_b[o] + sum_k h2[t][k]*fc_W[o][k]
// ---------------------------------------------------------------------------
__global__ __launch_bounds__(256, 1)
void fc_kernel(const float* __restrict__ h2, const float* __restrict__ fcW,
               const float* __restrict__ fcb, float* __restrict__ out)
{
    __shared__ float wls[5 * HID];
    __shared__ float bls[5];
    for (int i = threadIdx.x; i < 5 * HID; i += 256) wls[i] = fcW[i];
    if (threadIdx.x < 5) bls[threadIdx.x] = fcb[threadIdx.x];
    __syncthreads();

    const int t = blockIdx.x * blockDim.x + threadIdx.x;
    if (t >= T_SEQ) return;
    const float* hrow = h2 + (size_t)t * HID;
    float a0 = bls[0], a1 = bls[1], a2 = bls[2], a3 = bls[3], a4 = bls[4];
#pragma unroll
    for (int k = 0; k < HID; ++k) {
        float hv = hrow[k];
        a0 = fmaf(hv, wls[k], a0);
        a1 = fmaf(hv, wls[HID + k], a1);
        a2 = fmaf(hv, wls[2 * HID + k], a2);
        a3 = fmaf(hv, wls[3 * HID + k], a3);
        a4 = fmaf(hv, wls[4 * HID + k], a4);
    }
    float* orow = out + (size_t)t * 5;
    orow[0] = a0; orow[1] = a1; orow[2] = a2; orow[3] = a3; orow[4] = a4;
}

// ---------------------------------------------------------------------------
extern "C" void kernel_launch(void* const* d_in, const int* in_sizes, int n_in,
                              void* d_out, int out_size, void* d_ws, size_t ws_size,
                              hipStream_t stream) {
    const float* x    = (const float*)d_in[0];
    const float* Wih1 = (const float*)d_in[1];
    const float* Whh1 = (const float*)d_in[2];
    const float* bih1 = (const float*)d_in[3];
    const float* bhh1 = (const float*)d_in[4];
    const float* Wih2 = (const float*)d_in[5];
    const float* Whh2 = (const float*)d_in[6];
    const float* bih2 = (const float*)d_in[7];
    const float* bhh2 = (const float*)d_in[8];
    const float* fcW  = (const float*)d_in[9];
    const float* fcb  = (const float*)d_in[10];
    float* out = (float*)d_out;

    float* pre1  = (float*)d_ws;                       // [16384][512] fp32 = 32 MB
    float* h2buf = pre1 + (size_t)T_SEQ * G4;          // [16384][128] fp32 =  8 MB

    pre1_gemm<<<T_SEQ / 16, 512, 0, stream>>>(x, Wih1, bih1, bhh1, pre1);
    lstm_scan<<<1, 512, 0, stream>>>(pre1, Whh1, Wih2, Whh2, bih2, bhh2, h2buf);
    fc_kernel<<<(T_SEQ + 255) / 256, 256, 0, stream>>>(h2buf, fcW, fcb, out);
}

// Round 2
// 19413.640 us; speedup vs baseline: 3.4475x; 3.4475x over previous
//
#include <hip/hip_runtime.h>

#define T_SEQ 16384
#define HID   128
#define G4    512   // 4*HID

typedef _Float16 half2t __attribute__((ext_vector_type(2)));

__device__ __forceinline__ float sigm(float x) {
    float e = __expf(-x);
    return __builtin_amdgcn_rcpf(1.0f + e);
}
__device__ __forceinline__ float tanh_(float x) {
    float e = __expf(-2.0f * x);
    return __builtin_amdgcn_rcpf(1.0f + e) * 2.0f - 1.0f;
}
__device__ __forceinline__ half2t pack2(float lo, float hi) {
    half2t v; v.x = (_Float16)lo; v.y = (_Float16)hi; return v;
}

// ---------------------------------------------------------------------------
// Kernel 1: pre1[t][r] = (b_ih1[r]+b_hh1[r]) + sum_k x[t][k]*W_ih1[r][k]
// ---------------------------------------------------------------------------
__global__ __launch_bounds__(512, 1)
void pre1_gemm(const float* __restrict__ x, const float* __restrict__ Wih1,
               const float* __restrict__ bih1, const float* __restrict__ bhh1,
               float* __restrict__ pre1)
{
    __shared__ float xs[16][50];
    const int r  = threadIdx.x;
    const int t0 = blockIdx.x * 16;
    for (int i = r; i < 16 * 50; i += 512) xs[i / 50][i % 50] = x[t0 * 50 + i];
    __syncthreads();

    float wr[50];
#pragma unroll
    for (int k = 0; k < 50; ++k) wr[k] = Wih1[r * 50 + k];
    const float bias = bih1[r] + bhh1[r];

    for (int tt = 0; tt < 16; ++tt) {
        float acc = bias;
#pragma unroll
        for (int k = 0; k < 50; ++k) acc = fmaf(wr[k], xs[tt][k], acc);
        pre1[(size_t)(t0 + tt) * G4 + r] = acc;
    }
}

// ---------------------------------------------------------------------------
// Kernel 2: sequential 2-layer LSTM scan. ONE workgroup, 1024 threads (16
// waves, 4/SIMD -> hard 128-VGPR cap, so the 96 weight regs/thread cannot
// spill-cap us like the 512-thread/192-reg version did).
// Thread t: row = t&511, half = t>>9 (k in [64*half, 64*half+64)).
// Owns length-64 sub-rows of Whh1, Wih2, Whh2 as 3x32 packed-f16 VGPRs.
// Layer 2 runs one step lagged: superstep s computes L1 step s and L2 step
// s-1; all dots read only previous-superstep state (double-buffered H).
// Partial sums combined via LDS by the gate phase (256 unit-threads).
// ---------------------------------------------------------------------------
__global__ __launch_bounds__(1024, 1) __attribute__((amdgpu_waves_per_eu(4, 4)))
void lstm_scan(const float* __restrict__ pre1,
               const float* __restrict__ Whh1,
               const float* __restrict__ Wih2,
               const float* __restrict__ Whh2,
               const float* __restrict__ bih2,
               const float* __restrict__ bhh2,
               float* __restrict__ h2out)
{
    const int tid  = threadIdx.x;
    const int row  = tid & 511;   // row in [0,512)
    const int half = tid >> 9;    // 0: k=[0,64), 1: k=[64,128)

    __shared__ __align__(16) _Float16 H1[2][HID];   // h1 state, f16, dbuf
    __shared__ __align__(16) _Float16 H2[2][HID];
    __shared__ float P1[2][G4];                     // L1 partials [half][row]
    __shared__ float P2[4][G4];                     // L2 partials [ih0,ih1,hh0,hh1][row]

    {   // zero initial hidden state
        _Float16* p1 = &H1[0][0];
        _Float16* p2 = &H2[0][0];
        for (int k = tid; k < 2 * HID; k += 1024) { p1[k] = (_Float16)0.f; p2[k] = (_Float16)0.f; }
    }

    // ---- weights into registers: 3 x 32 half2 = 96 VGPRs ----
    half2t w1[32], w2a[32], w2b[32];
    {
        const float4* a = (const float4*)(Whh1 + (size_t)row * HID + half * 64);
        const float4* b = (const float4*)(Wih2 + (size_t)row * HID + half * 64);
        const float4* c = (const float4*)(Whh2 + (size_t)row * HID + half * 64);
#pragma unroll
        for (int k = 0; k < 16; ++k) {
            float4 va = a[k]; w1[2 * k] = pack2(va.x, va.y); w1[2 * k + 1] = pack2(va.z, va.w);
        }
#pragma unroll
        for (int k = 0; k < 16; ++k) {
            float4 vb = b[k]; w2a[2 * k] = pack2(vb.x, vb.y); w2a[2 * k + 1] = pack2(vb.z, vb.w);
        }
#pragma unroll
        for (int k = 0; k < 16; ++k) {
            float4 vc = c[k]; w2b[2 * k] = pack2(vc.x, vc.y); w2b[2 * k + 1] = pack2(vc.z, vc.w);
        }
    }
    // bias2 folded into the half-0 ih partial
    const float bias2r = (half == 0) ? (bih2[row] + bhh2[row]) : 0.f;

    float c1 = 0.f, c2 = 0.f;               // cell state (unit threads only)

    const float* prep = pre1 + row;
    float pre_cur = (half == 0) ? prep[0] : 0.f;
    __syncthreads();

    for (int s = 0; s <= T_SEQ; ++s) {
        const int rs    = s & 1;
        const int wslot = rs ^ 1;

        // prefetch next step's pre1 value
        float pre_nxt = 0.f;
        if (half == 0 && s + 1 < T_SEQ) pre_nxt = prep[(size_t)(s + 1) * G4];

        // ---------------- dot phase ----------------
        {
            const float4* hp1 = (const float4*)&H1[rs][half * 64];  // 8 x 16B
            const float4* hp2 = (const float4*)&H2[rs][half * 64];
            float a1 = pre_cur;   // L1 row partial (pre already has bias1)
            float a2 = bias2r;    // L2 ih partial
            float ab = 0.f;       // L2 hh partial
#pragma unroll
            for (int c = 0; c < 8; ++c) {
                float4 v = hp1[c];
                half2t v0 = __builtin_bit_cast(half2t, v.x);
                half2t v1 = __builtin_bit_cast(half2t, v.y);
                half2t v2 = __builtin_bit_cast(half2t, v.z);
                half2t v3 = __builtin_bit_cast(half2t, v.w);
                a1 = __builtin_amdgcn_fdot2(w1[4 * c + 0], v0, a1, false);
                a1 = __builtin_amdgcn_fdot2(w1[4 * c + 1], v1, a1, false);
                a1 = __builtin_amdgcn_fdot2(w1[4 * c + 2], v2, a1, false);
                a1 = __builtin_amdgcn_fdot2(w1[4 * c + 3], v3, a1, false);
                a2 = __builtin_amdgcn_fdot2(w2a[4 * c + 0], v0, a2, false);
                a2 = __builtin_amdgcn_fdot2(w2a[4 * c + 1], v1, a2, false);
                a2 = __builtin_amdgcn_fdot2(w2a[4 * c + 2], v2, a2, false);
                a2 = __builtin_amdgcn_fdot2(w2a[4 * c + 3], v3, a2, false);
            }
#pragma unroll
            for (int c = 0; c < 8; ++c) {
                float4 v = hp2[c];
                ab = __builtin_amdgcn_fdot2(w2b[4 * c + 0], __builtin_bit_cast(half2t, v.x), ab, false);
                ab = __builtin_amdgcn_fdot2(w2b[4 * c + 1], __builtin_bit_cast(half2t, v.y), ab, false);
                ab = __builtin_amdgcn_fdot2(w2b[4 * c + 2], __builtin_bit_cast(half2t, v.z), ab, false);
                ab = __builtin_amdgcn_fdot2(w2b[4 * c + 3], __builtin_bit_cast(half2t, v.w), ab, false);
            }
            if (s < T_SEQ) P1[half][row] = a1;
            if (s >= 1) { P2[half][row] = a2; P2[2 + half][row] = ab; }
        }
        __syncthreads();

        // ---------------- gate phase ----------------
        if (s < T_SEQ && tid < 128) {            // layer-1 unit u = tid
            const int u = tid;
            float gi = P1[0][u]           + P1[1][u];
            float gf = P1[0][HID + u]     + P1[1][HID + u];
            float gg = P1[0][2 * HID + u] + P1[1][2 * HID + u];
            float go = P1[0][3 * HID + u] + P1[1][3 * HID + u];
            float i_ = sigm(gi), f_ = sigm(gf), g_ = tanh_(gg), o_ = sigm(go);
            c1 = f_ * c1 + i_ * g_;
            H1[wslot][u] = (_Float16)(o_ * tanh_(c1));
        }
        if (s >= 1 && tid >= 128 && tid < 256) { // layer-2 unit u, step s-1
            const int u = tid - 128;
            float gi = (P2[0][u] + P2[1][u]) + (P2[2][u] + P2[3][u]);
            float gf = (P2[0][HID + u] + P2[1][HID + u]) + (P2[2][HID + u] + P2[3][HID + u]);
            float gg = (P2[0][2 * HID + u] + P2[1][2 * HID + u]) + (P2[2][2 * HID + u] + P2[3][2 * HID + u]);
            float go = (P2[0][3 * HID + u] + P2[1][3 * HID + u]) + (P2[2][3 * HID + u] + P2[3][3 * HID + u]);
            float i_ = sigm(gi), f_ = sigm(gf), g_ = tanh_(gg), o_ = sigm(go);
            c2 = f_ * c2 + i_ * g_;
            float h = o_ * tanh_(c2);
            H2[wslot][u] = (_Float16)h;
            h2out[(size_t)(s - 1) * HID + u] = h;
        }
        __syncthreads();

        pre_cur = pre_nxt;
    }
}

// ---------------------------------------------------------------------------
// Kernel 3: out[t][o] = fc_b[o] + sum_k h2[t][k]*fc_W[o][k]
// ---------------------------------------------------------------------------
__global__ __launch_bounds__(256, 1)
void fc_kernel(const float* __restrict__ h2, const float* __restrict__ fcW,
               const float* __restrict__ fcb, float* __restrict__ out)
{
    __shared__ float wls[5 * HID];
    __shared__ float bls[5];
    for (int i = threadIdx.x; i < 5 * HID; i += 256) wls[i] = fcW[i];
    if (threadIdx.x < 5) bls[threadIdx.x] = fcb[threadIdx.x];
    __syncthreads();

    const int t = blockIdx.x * blockDim.x + threadIdx.x;
    if (t >= T_SEQ) return;
    const float* hrow = h2 + (size_t)t * HID;
    float a0 = bls[0], a1 = bls[1], a2 = bls[2], a3 = bls[3], a4 = bls[4];
#pragma unroll
    for (int k = 0; k < HID; ++k) {
        float hv = hrow[k];
        a0 = fmaf(hv, wls[k], a0);
        a1 = fmaf(hv, wls[HID + k], a1);
        a2 = fmaf(hv, wls[2 * HID + k], a2);
        a3 = fmaf(hv, wls[3 * HID + k], a3);
        a4 = fmaf(hv, wls[4 * HID + k], a4);
    }
    float* orow = out + (size_t)t * 5;
    orow[0] = a0; orow[1] = a1; orow[2] = a2; orow[3] = a3; orow[4] = a4;
}

// ---------------------------------------------------------------------------
extern "C" void kernel_launch(void* const* d_in, const int* in_sizes, int n_in,
                              void* d_out, int out_size, void* d_ws, size_t ws_size,
                              hipStream_t stream) {
    const float* x    = (const float*)d_in[0];
    const float* Wih1 = (const float*)d_in[1];
    const float* Whh1 = (const float*)d_in[2];
    const float* bih1 = (const float*)d_in[3];
    const float* bhh1 = (const float*)d_in[4];
    const float* Wih2 = (const float*)d_in[5];
    const float* Whh2 = (const float*)d_in[6];
    const float* bih2 = (const float*)d_in[7];
    const float* bhh2 = (const float*)d_in[8];
    const float* fcW  = (const float*)d_in[9];
    const float* fcb  = (const float*)d_in[10];
    float* out = (float*)d_out;

    float* pre1  = (float*)d_ws;                       // [16384][512] fp32 = 32 MB
    float* h2buf = pre1 + (size_t)T_SEQ * G4;          // [16384][128] fp32 =  8 MB

    pre1_gemm<<<T_SEQ / 16, 512, 0, stream>>>(x, Wih1, bih1, bhh1, pre1);
    lstm_scan<<<1, 1024, 0, stream>>>(pre1, Whh1, Wih2, Whh2, bih2, bhh2, h2buf);
    fc_kernel<<<(T_SEQ + 255) / 256, 256, 0, stream>>>(h2buf, fcW, fcb, out);
}

// Round 3
// 14975.165 us; speedup vs baseline: 4.4694x; 1.2964x over previous
//
#include <hip/hip_runtime.h>

#define T_SEQ 16384
#define HID   128
#define G4    512   // 4*HID
#define CHUNK 8
#define RING_SLOTS 256
#define RING_CHUNKS (RING_SLOTS / CHUNK)   // 32

typedef _Float16 half2t __attribute__((ext_vector_type(2)));

__device__ __forceinline__ float sigm(float x) {
    float e = __expf(-x);
    return __builtin_amdgcn_rcpf(1.0f + e);
}
__device__ __forceinline__ float tanh_(float x) {
    float e = __expf(-2.0f * x);
    return __builtin_amdgcn_rcpf(1.0f + e) * 2.0f - 1.0f;
}
__device__ __forceinline__ half2t pack2(float lo, float hi) {
    half2t v; v.x = (_Float16)lo; v.y = (_Float16)hi; return v;
}
// raw barrier: drains LDS ops only; global (ring/pre1) ops stay in flight.
__device__ __forceinline__ void bar() {
    asm volatile("s_waitcnt lgkmcnt(0)" ::: "memory");
    __builtin_amdgcn_s_barrier();
    asm volatile("" ::: "memory");
}

// ---------------------------------------------------------------------------
// Kernel 1: pre1[t][r] = (b_ih1[r]+b_hh1[r]) + sum_k x[t][k]*W_ih1[r][k]
// ---------------------------------------------------------------------------
__global__ __launch_bounds__(512, 1)
void pre1_gemm(const float* __restrict__ x, const float* __restrict__ Wih1,
               const float* __restrict__ bih1, const float* __restrict__ bhh1,
               float* __restrict__ pre1)
{
    __shared__ float xs[16][50];
    const int r  = threadIdx.x;
    const int t0 = blockIdx.x * 16;
    for (int i = r; i < 16 * 50; i += 512) xs[i / 50][i % 50] = x[t0 * 50 + i];
    __syncthreads();

    float wr[50];
#pragma unroll
    for (int k = 0; k < 50; ++k) wr[k] = Wih1[r * 50 + k];
    const float bias = bih1[r] + bhh1[r];

    for (int tt = 0; tt < 16; ++tt) {
        float acc = bias;
#pragma unroll
        for (int k = 0; k < 50; ++k) acc = fmaf(wr[k], xs[tt][k], acc);
        pre1[(size_t)(t0 + tt) * G4 + r] = acc;
    }
}

// ---------------------------------------------------------------------------
// Kernel 2: 2-block persistent pipeline.
//  Block 0 (stage A): L1 scan; at superstep s also computes
//    pre2[s-1] = b2 + W_ih2 @ h1[s-1] (shares the h1 LDS reads with the L1
//    dot) and publishes it to a 256-slot ring; flag released per 8 steps.
//  Block 1 (stage B): consumes pre2 ring, runs L2 recurrence W_hh2 @ h2.
//  Each block: 1024 threads, row = tid&511, half = tid>>9 (64-wide sub-dot).
//  Weight regs/thread: A = 64 half2, B = 32 half2 -> both far under the
//  128-VGPR cap for 16-wave blocks: no spill regardless of allocator mood.
// ---------------------------------------------------------------------------
__global__ __launch_bounds__(1024, 4)
void lstm_pipe(const float* __restrict__ pre1,
               const float* __restrict__ Whh1,
               const float* __restrict__ Wih2,
               const float* __restrict__ Whh2,
               const float* __restrict__ bih2,
               const float* __restrict__ bhh2,
               unsigned* __restrict__ ring,      // [RING_SLOTS][G4] f32 bits
               unsigned* __restrict__ produced,  // chunks published by A
               unsigned* __restrict__ consumed,  // chunks retired by B
               float* __restrict__ h2out)
{
    const int tid  = threadIdx.x;
    const int row  = tid & 511;
    const int half = tid >> 9;

    __shared__ __align__(16) _Float16 HS[2][HID];   // h state (h1 in A, h2 in B)
    __shared__ float PA[2][G4];                     // main partials [half][row]
    __shared__ float PB[2][G4];                     // A only: pre2 partials

    for (int k = tid; k < 2 * HID; k += 1024) ((_Float16*)HS)[k] = (_Float16)0.f;

    if (blockIdx.x == 0) {
        // ================= stage A: layer 1 + pre2 producer =================
        half2t w1[32], w2a[32];
        {
            const float4* a = (const float4*)(Whh1 + (size_t)row * HID + half * 64);
            const float4* b = (const float4*)(Wih2 + (size_t)row * HID + half * 64);
#pragma unroll
            for (int k = 0; k < 16; ++k) {
                float4 va = a[k]; w1[2 * k] = pack2(va.x, va.y); w1[2 * k + 1] = pack2(va.z, va.w);
            }
#pragma unroll
            for (int k = 0; k < 16; ++k) {
                float4 vb = b[k]; w2a[2 * k] = pack2(vb.x, vb.y); w2a[2 * k + 1] = pack2(vb.z, vb.w);
            }
        }
        const float bias2r = (half == 0) ? (bih2[row] + bhh2[row]) : 0.f;
        float c1 = 0.f;
        const float* prep = pre1 + row;
        float pre_cur = (half == 0) ? prep[0] : 0.f;
        __syncthreads();

        for (int s = 0; s <= T_SEQ; ++s) {
            const int rs = s & 1, wslot = rs ^ 1;

            // chunk bookkeeping (wave 8 only; others run ahead to bar #1)
            if (tid == 512 && s >= 1 && ((s - 1) & 7) == 0) {
                const int cw = (s - 1) >> 3;            // chunk being written now
                if (cw >= RING_CHUNKS) {                // ring back-pressure
                    while ((int)__hip_atomic_load(consumed, __ATOMIC_ACQUIRE,
                                                  __HIP_MEMORY_SCOPE_AGENT) < cw - (RING_CHUNKS - 1))
                        __builtin_amdgcn_s_sleep(8);
                }
                if ((s - 1) >= CHUNK)                   // chunks 0..cw-1 complete+drained
                    __hip_atomic_store(produced, (unsigned)cw, __ATOMIC_RELEASE,
                                       __HIP_MEMORY_SCOPE_AGENT);
            }

            float pre_nxt = 0.f;
            if (half == 0 && s + 1 < T_SEQ) pre_nxt = prep[(size_t)(s + 1) * G4];

            {   // dots: L1 (a1) and W_ih2@h1 (a2) share the h1 chunk loads
                const float4* hp = (const float4*)&HS[rs][half * 64];
                float a1 = pre_cur, a2 = bias2r;
#pragma unroll
                for (int c = 0; c < 8; ++c) {
                    float4 v = hp[c];
                    half2t v0 = __builtin_bit_cast(half2t, v.x);
                    half2t v1 = __builtin_bit_cast(half2t, v.y);
                    half2t v2 = __builtin_bit_cast(half2t, v.z);
                    half2t v3 = __builtin_bit_cast(half2t, v.w);
                    a1 = __builtin_amdgcn_fdot2(w1[4 * c + 0], v0, a1, false);
                    a1 = __builtin_amdgcn_fdot2(w1[4 * c + 1], v1, a1, false);
                    a1 = __builtin_amdgcn_fdot2(w1[4 * c + 2], v2, a1, false);
                    a1 = __builtin_amdgcn_fdot2(w1[4 * c + 3], v3, a1, false);
                    a2 = __builtin_amdgcn_fdot2(w2a[4 * c + 0], v0, a2, false);
                    a2 = __builtin_amdgcn_fdot2(w2a[4 * c + 1], v1, a2, false);
                    a2 = __builtin_amdgcn_fdot2(w2a[4 * c + 2], v2, a2, false);
                    a2 = __builtin_amdgcn_fdot2(w2a[4 * c + 3], v3, a2, false);
                }
                if (s < T_SEQ) PA[half][row] = a1;
                PB[half][row] = a2;
            }
            bar();

            if (s < T_SEQ && tid < 128) {                 // L1 gates, unit u=tid
                const int u = tid;
                float gi = PA[0][u] + PA[1][u];
                float gf = PA[0][HID + u] + PA[1][HID + u];
                float gg = PA[0][2 * HID + u] + PA[1][2 * HID + u];
                float go = PA[0][3 * HID + u] + PA[1][3 * HID + u];
                float i_ = sigm(gi), f_ = sigm(gf), g_ = tanh_(gg), o_ = sigm(go);
                c1 = f_ * c1 + i_ * g_;
                HS[wslot][u] = (_Float16)(o_ * tanh_(c1));
            }
            if (s >= 1 && tid >= 512) {                   // publish pre2[s-1]
                const int r2 = tid - 512;
                float v = PB[0][r2] + PB[1][r2];
                __hip_atomic_store(&ring[(size_t)((s - 1) & (RING_SLOTS - 1)) * G4 + r2],
                                   __float_as_uint(v), __ATOMIC_RELAXED,
                                   __HIP_MEMORY_SCOPE_AGENT);
                if (((s - 1) & 7) == 7)                   // drain once per chunk
                    asm volatile("s_waitcnt vmcnt(0)" ::: "memory");
            }
            bar();
            pre_cur = pre_nxt;
        }
        if (tid == 512)
            __hip_atomic_store(produced, (unsigned)(T_SEQ / CHUNK), __ATOMIC_RELEASE,
                               __HIP_MEMORY_SCOPE_AGENT);
    } else {
        // ================= stage B: layer 2 consumer =================
        half2t w2b[32];
        {
            const float4* c = (const float4*)(Whh2 + (size_t)row * HID + half * 64);
#pragma unroll
            for (int k = 0; k < 16; ++k) {
                float4 vc = c[k]; w2b[2 * k] = pack2(vc.x, vc.y); w2b[2 * k + 1] = pack2(vc.z, vc.w);
            }
        }
        float c2 = 0.f;
        float pp[CHUNK];
        __syncthreads();

        for (int tb = 0; tb < T_SEQ; tb += CHUNK) {
            if (tid == 0) {
                if (tb > 0)
                    __hip_atomic_store(consumed, (unsigned)(tb >> 3), __ATOMIC_RELEASE,
                                       __HIP_MEMORY_SCOPE_AGENT);
                const unsigned need = (unsigned)((tb >> 3) + 1);
                while (__hip_atomic_load(produced, __ATOMIC_ACQUIRE,
                                         __HIP_MEMORY_SCOPE_AGENT) < need)
                    __builtin_amdgcn_s_sleep(8);
            }
            bar();
            if (half == 0) {
#pragma unroll
                for (int j = 0; j < CHUNK; ++j)
                    pp[j] = __uint_as_float(
                        __hip_atomic_load(&ring[(size_t)((tb + j) & (RING_SLOTS - 1)) * G4 + row],
                                          __ATOMIC_RELAXED, __HIP_MEMORY_SCOPE_AGENT));
            }
#pragma unroll
            for (int j = 0; j < CHUNK; ++j) {
                const int t = tb + j;
                const int rs = j & 1, wslot = rs ^ 1;
                {
                    const float4* hp = (const float4*)&HS[rs][half * 64];
                    float ab = 0.f;
#pragma unroll
                    for (int c = 0; c < 8; ++c) {
                        float4 v = hp[c];
                        ab = __builtin_amdgcn_fdot2(w2b[4 * c + 0], __builtin_bit_cast(half2t, v.x), ab, false);
                        ab = __builtin_amdgcn_fdot2(w2b[4 * c + 1], __builtin_bit_cast(half2t, v.y), ab, false);
                        ab = __builtin_amdgcn_fdot2(w2b[4 * c + 2], __builtin_bit_cast(half2t, v.z), ab, false);
                        ab = __builtin_amdgcn_fdot2(w2b[4 * c + 3], __builtin_bit_cast(half2t, v.w), ab, false);
                    }
                    PA[half][row] = ab + (half == 0 ? pp[j] : 0.f);
                }
                bar();
                if (tid < 128) {                          // L2 gates, unit u=tid
                    const int u = tid;
                    float gi = PA[0][u] + PA[1][u];
                    float gf = PA[0][HID + u] + PA[1][HID + u];
                    float gg = PA[0][2 * HID + u] + PA[1][2 * HID + u];
                    float go = PA[0][3 * HID + u] + PA[1][3 * HID + u];
                    float i_ = sigm(gi), f_ = sigm(gf), g_ = tanh_(gg), o_ = sigm(go);
                    c2 = f_ * c2 + i_ * g_;
                    float h = o_ * tanh_(c2);
                    HS[wslot][u] = (_Float16)h;
                    h2out[(size_t)t * HID + u] = h;
                }
                bar();
            }
        }
    }
}

// ---------------------------------------------------------------------------
// Kernel 3: out[t][o] = fc_b[o] + sum_k h2[t][k]*fc_W[o][k]
// ---------------------------------------------------------------------------
__global__ __launch_bounds__(256, 1)
void fc_kernel(const float* __restrict__ h2, const float* __restrict__ fcW,
               const float* __restrict__ fcb, float* __restrict__ out)
{
    __shared__ float wls[5 * HID];
    __shared__ float bls[5];
    for (int i = threadIdx.x; i < 5 * HID; i += 256) wls[i] = fcW[i];
    if (threadIdx.x < 5) bls[threadIdx.x] = fcb[threadIdx.x];
    __syncthreads();

    const int t = blockIdx.x * blockDim.x + threadIdx.x;
    if (t >= T_SEQ) return;
    const float* hrow = h2 + (size_t)t * HID;
    float a0 = bls[0], a1 = bls[1], a2 = bls[2], a3 = bls[3], a4 = bls[4];
#pragma unroll
    for (int k = 0; k < HID; ++k) {
        float hv = hrow[k];
        a0 = fmaf(hv, wls[k], a0);
        a1 = fmaf(hv, wls[HID + k], a1);
        a2 = fmaf(hv, wls[2 * HID + k], a2);
        a3 = fmaf(hv, wls[3 * HID + k], a3);
        a4 = fmaf(hv, wls[4 * HID + k], a4);
    }
    float* orow = out + (size_t)t * 5;
    orow[0] = a0; orow[1] = a1; orow[2] = a2; orow[3] = a3; orow[4] = a4;
}

// ---------------------------------------------------------------------------
extern "C" void kernel_launch(void* const* d_in, const int* in_sizes, int n_in,
                              void* d_out, int out_size, void* d_ws, size_t ws_size,
                              hipStream_t stream) {
    const float* x    = (const float*)d_in[0];
    const float* Wih1 = (const float*)d_in[1];
    const float* Whh1 = (const float*)d_in[2];
    const float* bih1 = (const float*)d_in[3];
    const float* bhh1 = (const float*)d_in[4];
    const float* Wih2 = (const float*)d_in[5];
    const float* Whh2 = (const float*)d_in[6];
    const float* bih2 = (const float*)d_in[7];
    const float* bhh2 = (const float*)d_in[8];
    const float* fcW  = (const float*)d_in[9];
    const float* fcb  = (const float*)d_in[10];
    float* out = (float*)d_out;

    // ws layout: pre1 32MB | h2buf 8MB | ring 512KB | counters
    float*    pre1  = (float*)d_ws;
    float*    h2buf = pre1 + (size_t)T_SEQ * G4;
    unsigned* ring  = (unsigned*)(h2buf + (size_t)T_SEQ * HID);
    unsigned* ctr   = ring + (size_t)RING_SLOTS * G4;   // produced=ctr[0], consumed=ctr[64]

    hipMemsetAsync(ctr, 0, 512, stream);
    pre1_gemm<<<T_SEQ / 16, 512, 0, stream>>>(x, Wih1, bih1, bhh1, pre1);
    lstm_pipe<<<2, 1024, 0, stream>>>(pre1, Whh1, Wih2, Whh2, bih2, bhh2,
                                      ring, ctr, ctr + 64, h2buf);
    fc_kernel<<<(T_SEQ + 255) / 256, 256, 0, stream>>>(h2buf, fcW, fcb, out);
}